// Round 3
// baseline (273.398 us; speedup 1.0000x reference)
//
#include <hip/hip_runtime.h>
#include <hip/hip_bf16.h>
#include <type_traits>

typedef __attribute__((ext_vector_type(8))) short bf16x8;
typedef __attribute__((ext_vector_type(4))) float floatx4;
typedef __attribute__((ext_vector_type(2))) float float2v;

__device__ __forceinline__ float bf2f(unsigned short u) {
    union { unsigned int x; float f; } v; v.x = ((unsigned int)u) << 16; return v.f;
}
__device__ __forceinline__ unsigned short f2bf(float f) {
    union { float f; unsigned int u; } v; v.f = f;
    unsigned int x = v.u;
    unsigned int r = x + 0x7fffu + ((x >> 16) & 1u);
    return (unsigned short)(r >> 16);
}
// packed f32x2 -> bf16x2 (RNE); compiler emits v_cvt_pk_bf16_f32
__device__ __forceinline__ unsigned int pk2bf(float lo, float hi) {
    float2 t; t.x = lo; t.y = hi;
    __hip_bfloat162 h = __float22bfloat162_rn(t);
    return *reinterpret_cast<unsigned int*>(&h);
}

// async global->LDS, 16B per lane; lds base must be wave-uniform (HW adds lane*16)
typedef const __attribute__((address_space(1))) unsigned int u32_g;
typedef __attribute__((address_space(3))) unsigned int u32_l;
__device__ __forceinline__ void gld_lds16(const void* g, void* l) {
    __builtin_amdgcn_global_load_lds((u32_g*)g, (u32_l*)l, 16, 0, 0);
}

// ---------------------------------------------------------------------------
// prep: fused  x->bf16 convert  +  w_qkv^T->bf16  +  w_proj^T->bf16
// ---------------------------------------------------------------------------
__device__ __forceinline__ void trans32(const float* __restrict__ in,
                                        unsigned short* __restrict__ out,
                                        int K, int N, int bx, int by,
                                        unsigned short (*T)[33]) {
    const int n0 = bx * 32, k0 = by * 32;
    const int r = threadIdx.x >> 3;
    const int c4 = (threadIdx.x & 7) * 4;
    float4 v = *reinterpret_cast<const float4*>(in + (size_t)(k0 + r) * N + n0 + c4);
    T[c4 + 0][r] = f2bf(v.x);
    T[c4 + 1][r] = f2bf(v.y);
    T[c4 + 2][r] = f2bf(v.z);
    T[c4 + 3][r] = f2bf(v.w);
    __syncthreads();
    ushort4 o = {T[r][c4], T[r][c4 + 1], T[r][c4 + 2], T[r][c4 + 3]};
    *reinterpret_cast<ushort4*>(out + (size_t)(n0 + r) * K + k0 + c4) = o;
}

__global__ __launch_bounds__(256) void prep(const float* __restrict__ x,
                                            unsigned short* __restrict__ xb,
                                            const float* __restrict__ wq,
                                            unsigned short* __restrict__ wqT,
                                            const float* __restrict__ wp,
                                            unsigned short* __restrict__ wpT) {
    __shared__ unsigned short T[32][33];
    const int b = blockIdx.x;
    if (b < 1024) {
        size_t i = ((size_t)b * 256 + threadIdx.x) * 8;
        float4 a = *reinterpret_cast<const float4*>(x + i);
        float4 c = *reinterpret_cast<const float4*>(x + i + 4);
        unsigned short t[8] = {f2bf(a.x), f2bf(a.y), f2bf(a.z), f2bf(a.w),
                               f2bf(c.x), f2bf(c.y), f2bf(c.z), f2bf(c.w)};
        *reinterpret_cast<uint4*>(xb + i) = *reinterpret_cast<const uint4*>(t);
    } else if (b < 4096) {
        int t = b - 1024;
        trans32(wq, wqT, 1024, 3072, t % 96, t / 96, T);
    } else {
        int t = b - 4096;
        trans32(wp, wpT, 1024, 1024, t % 32, t / 32, T);
    }
}

// ---------------------------------------------------------------------------
// gemm128 body (128x128, BK=32), 2-phase double-buffered pipeline (R1-measured).
// ---------------------------------------------------------------------------
__device__ __forceinline__ void gemm128_body(const unsigned short* __restrict__ A,
                                             const unsigned short* __restrict__ Bt,
                                             unsigned short* __restrict__ C,
                                             int bx, int by,
                                             unsigned short* __restrict__ S) {
    const int tid = threadIdx.x;
    const int wave = tid >> 6;
    const int lane = tid & 63;
    const int m15 = lane & 15;
    const int quad = lane >> 4;
    const int wm = wave >> 1;
    const int wn = wave & 1;
    const int m0 = by * 128;
    const int n0 = bx * 128;
    const int srow = lane >> 2;
    const int scol = (lane & 3) * 8;

    floatx4 acc[4][4];
#pragma unroll
    for (int mt = 0; mt < 4; mt++)
#pragma unroll
        for (int nt = 0; nt < 4; nt++) acc[mt][nt] = {0.f, 0.f, 0.f, 0.f};

    auto stage = [&](int k0, unsigned short* As, unsigned short* Bs) {
#pragma unroll
        for (int i = 0; i < 2; i++) {
            int j = wave * 2 + i;
            gld_lds16(A + (size_t)(m0 + j * 16 + srow) * 1024 + k0 + scol, &As[j * 16 * 32]);
            gld_lds16(Bt + (size_t)(n0 + j * 16 + srow) * 1024 + k0 + scol, &Bs[j * 16 * 32]);
        }
    };

    stage(0, S, S + 4096);
    __syncthreads();

    for (int kk = 0; kk < 32; ++kk) {
        unsigned short* As = S + (kk & 1) * 8192;
        unsigned short* Bs = As + 4096;
        if (kk < 31) {
            unsigned short* An = S + ((kk & 1) ^ 1) * 8192;
            stage((kk + 1) * 32, An, An + 4096);
        }

        bf16x8 a[4];
#pragma unroll
        for (int mt = 0; mt < 4; mt++)
            a[mt] = *reinterpret_cast<bf16x8*>(&As[(wm * 64 + mt * 16 + m15) * 32 + quad * 8]);
#pragma unroll
        for (int nt = 0; nt < 4; nt++) {
            bf16x8 b = *reinterpret_cast<bf16x8*>(&Bs[(wn * 64 + nt * 16 + m15) * 32 + quad * 8]);
#pragma unroll
            for (int mt = 0; mt < 4; mt++)
                acc[mt][nt] = __builtin_amdgcn_mfma_f32_16x16x32_bf16(a[mt], b, acc[mt][nt], 0, 0, 0);
        }
        __syncthreads();
    }

#pragma unroll
    for (int mt = 0; mt < 4; mt++)
#pragma unroll
        for (int nt = 0; nt < 4; nt++)
#pragma unroll
            for (int i = 0; i < 4; i++) {
                int row = m0 + wm * 64 + mt * 16 + quad * 4 + i;
                int col = n0 + wn * 64 + nt * 16 + m15;
                C[(size_t)row * 3072 + col] = f2bf(acc[mt][nt][i]);
            }
}

// ---------------------------------------------------------------------------
// RelPosBias body (v5, harness-verified).
// biasb stored swizzled: idx = row*2048 + (col&~63) + (col&15)*4 + ((col>>4)&3)
// Output = (mlp(rel)+b3)*log2(e) as bf16.
// ---------------------------------------------------------------------------
__device__ __forceinline__ void rpb_body(int bx,
                                         const float* __restrict__ rel,
                                         const float* __restrict__ w1,
                                         const float* __restrict__ b1,
                                         const float* __restrict__ w2,
                                         const float* __restrict__ b2,
                                         const float* __restrict__ w3,
                                         const float* __restrict__ b3,
                                         unsigned short* __restrict__ biasb) {
    const int tid = threadIdx.x;
    const int wave = tid >> 6;
    const int lane = tid & 63;
    const int m15 = lane & 15;
    const int quad = lane >> 4;

    bf16x8 af0, af1;
    {
        unsigned short t0[8], t1[8];
#pragma unroll
        for (int j = 0; j < 8; j++) {
            int k = quad * 8 + j;
            t0[j] = f2bf(w2[k * 32 + m15]);
            t1[j] = f2bf(w2[k * 32 + 16 + m15]);
        }
        af0 = *reinterpret_cast<bf16x8*>(t0);
        af1 = *reinterpret_cast<bf16x8*>(t1);
    }

    float2v w1a2[4], w1b2[4], b12[4];
#pragma unroll
    for (int p = 0; p < 4; p++) {
        int base = quad * 8 + 2 * p;
        w1a2[p] = {w1[base], w1[base + 1]};
        w1b2[p] = {w1[32 + base], w1[32 + base + 1]};
        b12[p]  = {b1[base], b1[base + 1]};
    }

    floatx4 b2r0, b2r1;
    float2v w3p00, w3p01, w3p10, w3p11;
    const float LOG2E = 1.44269504f;
    {
        float4 t0 = *reinterpret_cast<const float4*>(b2 + quad * 4);
        float4 t1 = *reinterpret_cast<const float4*>(b2 + 16 + quad * 4);
        b2r0 = {t0.x, t0.y, t0.z, t0.w};
        b2r1 = {t1.x, t1.y, t1.z, t1.w};
        float4 u0 = *reinterpret_cast<const float4*>(w3 + quad * 4);
        float4 u1 = *reinterpret_cast<const float4*>(w3 + 16 + quad * 4);
        w3p00 = {u0.x * LOG2E, u0.y * LOG2E};
        w3p01 = {u0.z * LOG2E, u0.w * LOG2E};
        w3p10 = {u1.x * LOG2E, u1.y * LOG2E};
        w3p11 = {u1.z * LOG2E, u1.w * LOG2E};
    }
    const float b3s = b3[0] * LOG2E;
    const float2v z2 = {0.f, 0.f};
    const floatx4 b3r = {b3s, b3s, b3s, b3s};

    bf16x8 sel;
    {
        unsigned short t[8];
#pragma unroll
        for (int j = 0; j < 8; j++)
            t[j] = (m15 == j) ? (unsigned short)0x3f80u : (unsigned short)0;
        sel = *reinterpret_cast<bf16x8*>(t);
    }

    const int base = bx * 1024 + wave * 64;

    float2 cur[4];
#pragma unroll
    for (int t = 0; t < 4; t++)
        cur[t] = *reinterpret_cast<const float2*>(rel + (size_t)(base + t * 16 + m15) * 2);

    for (int it = 0; it < 4; ++it) {
        const int pix0 = base + it * 256;
        float2 nxt[4];
        if (it < 3) {
#pragma unroll
            for (int t = 0; t < 4; t++)
                nxt[t] = *reinterpret_cast<const float2*>(rel + (size_t)(pix0 + 256 + t * 16 + m15) * 2);
        }

        float sreg[4];
#pragma unroll
        for (int t = 0; t < 4; t++) {
            float2v dx2 = {cur[t].x, cur[t].x}, dy2 = {cur[t].y, cur[t].y};

            unsigned int hp[4];
#pragma unroll
            for (int p = 0; p < 4; p++) {
                float2v h = __builtin_elementwise_fma(dx2, w1a2[p],
                             __builtin_elementwise_fma(dy2, w1b2[p], b12[p]));
                h = __builtin_elementwise_max(h, z2);
                hp[p] = __builtin_amdgcn_perm(__float_as_uint(h.y), __float_as_uint(h.x), 0x07060302u);
            }
            bf16x8 hb = *reinterpret_cast<bf16x8*>(hp);

            floatx4 d0 = __builtin_amdgcn_mfma_f32_16x16x32_bf16(af0, hb, b2r0, 0, 0, 0);
            floatx4 d1 = __builtin_amdgcn_mfma_f32_16x16x32_bf16(af1, hb, b2r1, 0, 0, 0);

            float2v m00 = __builtin_elementwise_max(__builtin_shufflevector(d0, d0, 0, 1), z2);
            float2v m01 = __builtin_elementwise_max(__builtin_shufflevector(d0, d0, 2, 3), z2);
            float2v m10 = __builtin_elementwise_max(__builtin_shufflevector(d1, d1, 0, 1), z2);
            float2v m11 = __builtin_elementwise_max(__builtin_shufflevector(d1, d1, 2, 3), z2);
            float2v acc2 = m00 * w3p00;
            acc2 = __builtin_elementwise_fma(m01, w3p01, acc2);
            acc2 = __builtin_elementwise_fma(m10, w3p10, acc2);
            acc2 = __builtin_elementwise_fma(m11, w3p11, acc2);
            sreg[t] = acc2.x + acc2.y;
        }

        unsigned int sb[4];
        sb[0] = (unsigned int)f2bf(sreg[0]) | ((unsigned int)f2bf(sreg[1]) << 16);
        sb[1] = (unsigned int)f2bf(sreg[2]) | ((unsigned int)f2bf(sreg[3]) << 16);
        sb[2] = 0; sb[3] = 0;
        bf16x8 sf = *reinterpret_cast<bf16x8*>(sb);
        floatx4 dsum = __builtin_amdgcn_mfma_f32_16x16x32_bf16(sel, sf, b3r, 0, 0, 0);

        if (quad == 0) {
            unsigned short o[4] = {f2bf(dsum[0]), f2bf(dsum[1]), f2bf(dsum[2]), f2bf(dsum[3])};
            *reinterpret_cast<ushort4*>(biasb + (size_t)pix0 + m15 * 4) =
                *reinterpret_cast<const ushort4*>(o);
        }

        if (it < 3) {
#pragma unroll
            for (int t = 0; t < 4; t++) cur[t] = nxt[t];
        }
    }
}

// ---------------------------------------------------------------------------
// Fused dispatch (R1-measured structure): blocks [0,384) = qkv GEMM,
// [384,4480) = rpb. Independent data; complementary pipes.
// ---------------------------------------------------------------------------
__global__ __launch_bounds__(256) void gemm_rpb(const unsigned short* __restrict__ xb,
                                                const unsigned short* __restrict__ wqT,
                                                unsigned short* __restrict__ qkv,
                                                const float* __restrict__ rel,
                                                const float* __restrict__ w1,
                                                const float* __restrict__ b1,
                                                const float* __restrict__ w2,
                                                const float* __restrict__ b2,
                                                const float* __restrict__ w3,
                                                const float* __restrict__ b3,
                                                unsigned short* __restrict__ biasb) {
    __shared__ __align__(16) unsigned short S[4 * 128 * 32];  // 32 KiB dbuf
    const int b = blockIdx.x;
    if (b < 384)
        gemm128_body(xb, wqT, qkv, b % 24, b / 24, S);
    else
        rpb_body(b - 384, rel, w1, b1, w2, b2, w3, b3, biasb);
}

// ---------------------------------------------------------------------------
// GEMM: BM=64 (used for proj), 2-phase double-buffered (R1-measured).
// ---------------------------------------------------------------------------
template<int BN, typename TC>
__global__ __launch_bounds__(256) void gemm_abt(const unsigned short* __restrict__ A,
                                                const unsigned short* __restrict__ Bt,
                                                TC* __restrict__ C,
                                                int M, int N, int K) {
    constexpr int NT = BN / 32;
    __shared__ __align__(16) unsigned short As[2][64 * 32];
    __shared__ __align__(16) unsigned short Bs[2][BN * 32];

    const int tid = threadIdx.x;
    const int wave = tid >> 6;
    const int lane = tid & 63;
    const int m15 = lane & 15;
    const int quad = lane >> 4;
    const int wm = wave >> 1;
    const int wn = wave & 1;
    const int m0 = blockIdx.y * 64;
    const int n0 = blockIdx.x * BN;

    const int srow = lane >> 2;
    const int scol = (lane & 3) * 8;

    floatx4 acc[2][NT];
#pragma unroll
    for (int mt = 0; mt < 2; mt++)
#pragma unroll
        for (int nt = 0; nt < NT; nt++) acc[mt][nt] = {0.f, 0.f, 0.f, 0.f};

    auto stage = [&](int k0, int buf) {
        gld_lds16(A + (size_t)(m0 + wave * 16 + srow) * K + k0 + scol, &As[buf][wave * 16 * 32]);
#pragma unroll
        for (int i = 0; i < BN / 64; i++) {
            int j = wave * (BN / 64) + i;
            gld_lds16(Bt + (size_t)(n0 + j * 16 + srow) * K + k0 + scol, &Bs[buf][j * 16 * 32]);
        }
    };

    const int nk = K >> 5;
    stage(0, 0);
    __syncthreads();

    for (int kk = 0; kk < nk; ++kk) {
        const int cur = kk & 1;
        if (kk + 1 < nk) stage((kk + 1) * 32, cur ^ 1);

        bf16x8 a[2];
#pragma unroll
        for (int mt = 0; mt < 2; mt++)
            a[mt] = *reinterpret_cast<bf16x8*>(&As[cur][(wm * 32 + mt * 16 + m15) * 32 + quad * 8]);
#pragma unroll
        for (int nt = 0; nt < NT; nt++) {
            bf16x8 b = *reinterpret_cast<bf16x8*>(&Bs[cur][(wn * (BN / 2) + nt * 16 + m15) * 32 + quad * 8]);
#pragma unroll
            for (int mt = 0; mt < 2; mt++)
                acc[mt][nt] = __builtin_amdgcn_mfma_f32_16x16x32_bf16(a[mt], b, acc[mt][nt], 0, 0, 0);
        }
        __syncthreads();
    }

#pragma unroll
    for (int mt = 0; mt < 2; mt++)
#pragma unroll
        for (int nt = 0; nt < NT; nt++)
#pragma unroll
            for (int i = 0; i < 4; i++) {
                int row = m0 + wm * 32 + mt * 16 + quad * 4 + i;
                int col = n0 + wn * (BN / 2) + nt * 16 + m15;
                if constexpr (std::is_same<TC, float>::value)
                    C[(size_t)row * N + col] = acc[mt][nt][i];
                else
                    C[(size_t)row * N + col] = f2bf(acc[mt][nt][i]);
            }
}

// ---------------------------------------------------------------------------
// Flash attention v3: operand-swapped QK^T (st = mfma(K, Q)) puts each q-row's
// scores lane-local (lane (quad,m15) holds S[key=nt*16+quad*4+i][q=m15]), so
// softmax + P->bf16 packing are register-only. The PV A-frag slot ordering is
// absorbed by storing V's key-COLUMN at sigma(key) = {b5,b3,b2,b4,b1,b0}
// (pure bit-permutation; preserves even/odd pairs so the packed u32 V-write
// is unchanged). P LDS round-trip eliminated: -18KiB LDS (54->36, 3 blk/CU at
// launch_bounds(512,6)), -16 u16 stores, -48 f2bf VALU per lane per tile;
// bias becomes 2 contiguous 16B loads (offset quad*16, index i*4+nt).
// ---------------------------------------------------------------------------
__global__ __launch_bounds__(512, 6) void attn_kernel(const unsigned short* __restrict__ qkv,
                                                      const unsigned short* __restrict__ biasb,
                                                      unsigned short* __restrict__ attn_out) {
    const int h = blockIdx.x;
    const int q0 = blockIdx.y * 64;
    __shared__ __align__(16) unsigned short Kst[2][64 * 72];
    __shared__ __align__(16) unsigned short Vst[2][64 * 72];  // [d][key-slot]

    const int tid = threadIdx.x;
    const int g = tid >> 8;
    const int w = (tid >> 6) & 3;
    const int lane = tid & 63;
    const int ltid = tid & 255;
    const int m15 = lane & 15;
    const int quad = lane >> 4;

    bf16x8 qf[2];
#pragma unroll
    for (int kh = 0; kh < 2; kh++)
        qf[kh] = *reinterpret_cast<const bf16x8*>(
            qkv + (size_t)(q0 + w * 16 + m15) * 3072 + h * 64 + kh * 32 + quad * 8);

    const int kr0 = ltid >> 3, kd0 = (ltid & 7) * 8;
    const int ka = (ltid & 31) * 2;
    const int vd0 = (ltid >> 5) * 8;
    // sigma(key): slot = {b5, b3, b2, b4, b1, b0}; ka even -> ska even, pair preserved
    const int ska = ((ka >> 5) & 1) * 32 + ((ka >> 2) & 3) * 8 + ((ka >> 4) & 1) * 4 + (ka & 3);

    unsigned short* Kc = Kst[g];
    unsigned short* Vc = Vst[g];
    const size_t kofs = (size_t)g * 1024;

    uint4 kreg0 = *reinterpret_cast<const uint4*>(qkv + (kofs + kr0) * 3072 + 1024 + h * 64 + kd0);
    uint4 kreg1 = *reinterpret_cast<const uint4*>(qkv + (kofs + kr0 + 32) * 3072 + 1024 + h * 64 + kd0);
    uint4 vrega = *reinterpret_cast<const uint4*>(qkv + (kofs + ka) * 3072 + 2048 + h * 64 + vd0);
    uint4 vregb = *reinterpret_cast<const uint4*>(qkv + (kofs + ka + 1) * 3072 + 2048 + h * 64 + vd0);

    // bias: 16 contiguous shorts per lane per k-tile at offset quad*16;
    // element (i*4+nt) = bias[q=m15-row][key=nt*16+quad*4+i]
    const unsigned short* bbase =
        biasb + (size_t)(q0 + w * 16 + m15) * 2048 + kofs + quad * 16;
    union BU { uint4 v[2]; unsigned short s[16]; };
    BU br, nbr;
    br.v[0] = *reinterpret_cast<const uint4*>(bbase);
    br.v[1] = *reinterpret_cast<const uint4*>(bbase + 8);

    float rs = 0.f;
    floatx4 acc[4];
#pragma unroll
    for (int i = 0; i < 4; i++) acc[i] = {0.f, 0.f, 0.f, 0.f};
    const float c1 = 0.125f * 1.44269504f;

    for (int kt = 0; kt < 16; ++kt) {
        __syncthreads();

        *reinterpret_cast<uint4*>(&Kc[kr0 * 72 + kd0]) = kreg0;
        *reinterpret_cast<uint4*>(&Kc[(kr0 + 32) * 72 + kd0]) = kreg1;
        {
            const unsigned int* aw = reinterpret_cast<const unsigned int*>(&vrega);
            const unsigned int* bw = reinterpret_cast<const unsigned int*>(&vregb);
#pragma unroll
            for (int wd = 0; wd < 4; wd++) {
                unsigned int lo = __builtin_amdgcn_perm(bw[wd], aw[wd], 0x05040100u);
                unsigned int hi = __builtin_amdgcn_perm(bw[wd], aw[wd], 0x07060302u);
                *reinterpret_cast<unsigned int*>(&Vc[(vd0 + 2 * wd) * 72 + ska]) = lo;
                *reinterpret_cast<unsigned int*>(&Vc[(vd0 + 2 * wd + 1) * 72 + ska]) = hi;
            }
        }
        __syncthreads();

        if (kt < 15) {
            const size_t kb = kofs + (size_t)(kt + 1) * 64;
            kreg0 = *reinterpret_cast<const uint4*>(qkv + (kb + kr0) * 3072 + 1024 + h * 64 + kd0);
            kreg1 = *reinterpret_cast<const uint4*>(qkv + (kb + kr0 + 32) * 3072 + 1024 + h * 64 + kd0);
            vrega = *reinterpret_cast<const uint4*>(qkv + (kb + ka) * 3072 + 2048 + h * 64 + vd0);
            vregb = *reinterpret_cast<const uint4*>(qkv + (kb + ka + 1) * 3072 + 2048 + h * 64 + vd0);
        }

        // swapped QK^T: st[nt][i] = S[key=nt*16+quad*4+i][q=m15]
        floatx4 st[4];
#pragma unroll
        for (int nt = 0; nt < 4; nt++) st[nt] = {0.f, 0.f, 0.f, 0.f};
        __builtin_amdgcn_s_setprio(1);
#pragma unroll
        for (int kh = 0; kh < 2; kh++) {
#pragma unroll
            for (int nt = 0; nt < 4; nt++) {
                bf16x8 kb = *reinterpret_cast<bf16x8*>(&Kc[(nt * 16 + m15) * 72 + kh * 32 + quad * 8]);
                st[nt] = __builtin_amdgcn_mfma_f32_16x16x32_bf16(kb, qf[kh], st[nt], 0, 0, 0);
            }
        }
        __builtin_amdgcn_s_setprio(0);

        if (kt < 15) {
            const unsigned short* nb = bbase + (size_t)(kt + 1) * 64;
            nbr.v[0] = *reinterpret_cast<const uint4*>(nb);
            nbr.v[1] = *reinterpret_cast<const uint4*>(nb + 8);
        }

        float p[4][4];
#pragma unroll
        for (int nt = 0; nt < 4; nt++)
#pragma unroll
            for (int i = 0; i < 4; i++) {
                float lg = fmaf(st[nt][i], c1, bf2f(br.s[i * 4 + nt]));
                p[nt][i] = __builtin_amdgcn_exp2f(lg);
                rs += p[nt][i];
            }

        // pack P into PV A-frags: slot j (kh,quad) -> p[2kh + (j>>2)][j&3] (local!)
        bf16x8 paf[2];
#pragma unroll
        for (int kh = 0; kh < 2; kh++) {
            unsigned int pw[4];
            pw[0] = pk2bf(p[2 * kh][0], p[2 * kh][1]);
            pw[1] = pk2bf(p[2 * kh][2], p[2 * kh][3]);
            pw[2] = pk2bf(p[2 * kh + 1][0], p[2 * kh + 1][1]);
            pw[3] = pk2bf(p[2 * kh + 1][2], p[2 * kh + 1][3]);
            paf[kh] = *reinterpret_cast<bf16x8*>(pw);
        }

        __builtin_amdgcn_s_setprio(1);
#pragma unroll
        for (int kh = 0; kh < 2; kh++) {
#pragma unroll
            for (int nt = 0; nt < 4; nt++) {
                bf16x8 vb = *reinterpret_cast<bf16x8*>(&Vc[(nt * 16 + m15) * 72 + kh * 32 + quad * 8]);
                acc[nt] = __builtin_amdgcn_mfma_f32_16x16x32_bf16(paf[kh], vb, acc[nt], 0, 0, 0);
            }
        }
        __builtin_amdgcn_s_setprio(0);

        if (kt < 15) { br.v[0] = nbr.v[0]; br.v[1] = nbr.v[1]; }
    }

    // reduce rs across quads: lane then holds full sum for q=m15 (this g)
    rs += __shfl_xor(rs, 16);
    rs += __shfl_xor(rs, 32);

    float* accbuf = reinterpret_cast<float*>(&Kst[0][0]);
    float* lbuf = accbuf + 4096;

    __syncthreads();
    if (g == 1) {
#pragma unroll
        for (int nt = 0; nt < 4; nt++)
#pragma unroll
            for (int i = 0; i < 4; i++)
                accbuf[(w * 16 + quad * 4 + i) * 64 + nt * 16 + m15] = acc[nt][i];
        if (lane < 16) lbuf[w * 16 + m15] = rs;
    }
    __syncthreads();
    if (g == 0) {
        float rq = rs + lbuf[w * 16 + m15];  // total for q=m15
        float linv[4];
#pragma unroll
        for (int i = 0; i < 4; i++)
            linv[i] = 1.f / __shfl(rq, quad * 4 + i);
#pragma unroll
        for (int nt = 0; nt < 4; nt++)
#pragma unroll
            for (int i = 0; i < 4; i++) {
                float o = (acc[nt][i] + accbuf[(w * 16 + quad * 4 + i) * 64 + nt * 16 + m15]) * linv[i];
                int row = q0 + w * 16 + quad * 4 + i;
                int col = h * 64 + nt * 16 + m15;
                attn_out[(size_t)row * 1024 + col] = f2bf(o);
            }
    }
}

extern "C" void kernel_launch(void* const* d_in, const int* in_sizes, int n_in,
                              void* d_out, int out_size, void* d_ws, size_t ws_size,
                              hipStream_t stream) {
    const float* x      = (const float*)d_in[0];
    const float* rel    = (const float*)d_in[1];
    const float* w_qkv  = (const float*)d_in[2];
    const float* w_proj = (const float*)d_in[3];
    const float* w1     = (const float*)d_in[4];
    const float* b1     = (const float*)d_in[5];
    const float* w2     = (const float*)d_in[6];
    const float* b2     = (const float*)d_in[7];
    const float* w3     = (const float*)d_in[8];
    const float* b3     = (const float*)d_in[9];

    char* ws = (char*)d_ws;
    unsigned short* qkv   = (unsigned short*)ws;                   // 12,582,912 B
    unsigned short* biasb = (unsigned short*)(ws + 12582912);      //  8,388,608 B (bf16, *log2e, swizzled)
    unsigned short* xb    = (unsigned short*)(ws + 20971520);      //  4,194,304 B (aliased with attn)
    unsigned short* attn  = xb;                                    //  xb dead after qkv GEMM
    unsigned short* wqT   = (unsigned short*)(ws + 25165824);      //  6,291,456 B
    unsigned short* wpT   = (unsigned short*)(ws + 31457280);      //  2,097,152 B  (= 32 MiB total)
    float* out = (float*)d_out;

    prep<<<5120, 256, 0, stream>>>(x, xb, w_qkv, wqT, w_proj, wpT);
    // fused: qkv GEMM (blocks 0-383) + RPB MLP (blocks 384-4479)
    gemm_rpb<<<4480, 256, 0, stream>>>(xb, wqT, qkv, rel, w1, b1, w2, b2, w3, b3, biasb);
    attn_kernel<<<dim3(16, 32), 512, 0, stream>>>(qkv, biasb, attn);
    gemm_abt<64, float><<<dim3(16, 32), 256, 0, stream>>>(attn, wpT, out, 2048, 1024, 1024);
}

// Round 4
// 205.449 us; speedup vs baseline: 1.3307x; 1.3307x over previous
//
#include <hip/hip_runtime.h>
#include <hip/hip_bf16.h>
#include <type_traits>

typedef __attribute__((ext_vector_type(8))) short bf16x8;
typedef __attribute__((ext_vector_type(4))) float floatx4;
typedef __attribute__((ext_vector_type(2))) float float2v;

__device__ __forceinline__ float bf2f(unsigned short u) {
    union { unsigned int x; float f; } v; v.x = ((unsigned int)u) << 16; return v.f;
}
__device__ __forceinline__ unsigned short f2bf(float f) {
    union { float f; unsigned int u; } v; v.f = f;
    unsigned int x = v.u;
    unsigned int r = x + 0x7fffu + ((x >> 16) & 1u);
    return (unsigned short)(r >> 16);
}
// packed f32x2 -> bf16x2 (RNE); compiler emits v_cvt_pk_bf16_f32
__device__ __forceinline__ unsigned int pk2bf(float lo, float hi) {
    float2 t; t.x = lo; t.y = hi;
    __hip_bfloat162 h = __float22bfloat162_rn(t);
    return *reinterpret_cast<unsigned int*>(&h);
}

// async global->LDS, 16B per lane; lds base must be wave-uniform (HW adds lane*16)
typedef const __attribute__((address_space(1))) unsigned int u32_g;
typedef __attribute__((address_space(3))) unsigned int u32_l;
__device__ __forceinline__ void gld_lds16(const void* g, void* l) {
    __builtin_amdgcn_global_load_lds((u32_g*)g, (u32_l*)l, 16, 0, 0);
}

// ---------------------------------------------------------------------------
// prep: fused  x->bf16 convert  +  w_qkv^T->bf16  +  w_proj^T->bf16
// ---------------------------------------------------------------------------
__device__ __forceinline__ void trans32(const float* __restrict__ in,
                                        unsigned short* __restrict__ out,
                                        int K, int N, int bx, int by,
                                        unsigned short (*T)[33]) {
    const int n0 = bx * 32, k0 = by * 32;
    const int r = threadIdx.x >> 3;
    const int c4 = (threadIdx.x & 7) * 4;
    float4 v = *reinterpret_cast<const float4*>(in + (size_t)(k0 + r) * N + n0 + c4);
    T[c4 + 0][r] = f2bf(v.x);
    T[c4 + 1][r] = f2bf(v.y);
    T[c4 + 2][r] = f2bf(v.z);
    T[c4 + 3][r] = f2bf(v.w);
    __syncthreads();
    ushort4 o = {T[r][c4], T[r][c4 + 1], T[r][c4 + 2], T[r][c4 + 3]};
    *reinterpret_cast<ushort4*>(out + (size_t)(n0 + r) * K + k0 + c4) = o;
}

__global__ __launch_bounds__(256) void prep(const float* __restrict__ x,
                                            unsigned short* __restrict__ xb,
                                            const float* __restrict__ wq,
                                            unsigned short* __restrict__ wqT,
                                            const float* __restrict__ wp,
                                            unsigned short* __restrict__ wpT) {
    __shared__ unsigned short T[32][33];
    const int b = blockIdx.x;
    if (b < 1024) {
        size_t i = ((size_t)b * 256 + threadIdx.x) * 8;
        float4 a = *reinterpret_cast<const float4*>(x + i);
        float4 c = *reinterpret_cast<const float4*>(x + i + 4);
        unsigned short t[8] = {f2bf(a.x), f2bf(a.y), f2bf(a.z), f2bf(a.w),
                               f2bf(c.x), f2bf(c.y), f2bf(c.z), f2bf(c.w)};
        *reinterpret_cast<uint4*>(xb + i) = *reinterpret_cast<const uint4*>(t);
    } else if (b < 4096) {
        int t = b - 1024;
        trans32(wq, wqT, 1024, 3072, t % 96, t / 96, T);
    } else {
        int t = b - 4096;
        trans32(wp, wpT, 1024, 1024, t % 32, t / 32, T);
    }
}

// ---------------------------------------------------------------------------
// gemm128 body (128x128, BK=32), 2-phase double-buffered pipeline (R1-measured).
// ---------------------------------------------------------------------------
__device__ __forceinline__ void gemm128_body(const unsigned short* __restrict__ A,
                                             const unsigned short* __restrict__ Bt,
                                             unsigned short* __restrict__ C,
                                             int bx, int by,
                                             unsigned short* __restrict__ S) {
    const int tid = threadIdx.x;
    const int wave = tid >> 6;
    const int lane = tid & 63;
    const int m15 = lane & 15;
    const int quad = lane >> 4;
    const int wm = wave >> 1;
    const int wn = wave & 1;
    const int m0 = by * 128;
    const int n0 = bx * 128;
    const int srow = lane >> 2;
    const int scol = (lane & 3) * 8;

    floatx4 acc[4][4];
#pragma unroll
    for (int mt = 0; mt < 4; mt++)
#pragma unroll
        for (int nt = 0; nt < 4; nt++) acc[mt][nt] = {0.f, 0.f, 0.f, 0.f};

    auto stage = [&](int k0, unsigned short* As, unsigned short* Bs) {
#pragma unroll
        for (int i = 0; i < 2; i++) {
            int j = wave * 2 + i;
            gld_lds16(A + (size_t)(m0 + j * 16 + srow) * 1024 + k0 + scol, &As[j * 16 * 32]);
            gld_lds16(Bt + (size_t)(n0 + j * 16 + srow) * 1024 + k0 + scol, &Bs[j * 16 * 32]);
        }
    };

    stage(0, S, S + 4096);
    __syncthreads();

    for (int kk = 0; kk < 32; ++kk) {
        unsigned short* As = S + (kk & 1) * 8192;
        unsigned short* Bs = As + 4096;
        if (kk < 31) {
            unsigned short* An = S + ((kk & 1) ^ 1) * 8192;
            stage((kk + 1) * 32, An, An + 4096);
        }

        bf16x8 a[4];
#pragma unroll
        for (int mt = 0; mt < 4; mt++)
            a[mt] = *reinterpret_cast<bf16x8*>(&As[(wm * 64 + mt * 16 + m15) * 32 + quad * 8]);
#pragma unroll
        for (int nt = 0; nt < 4; nt++) {
            bf16x8 b = *reinterpret_cast<bf16x8*>(&Bs[(wn * 64 + nt * 16 + m15) * 32 + quad * 8]);
#pragma unroll
            for (int mt = 0; mt < 4; mt++)
                acc[mt][nt] = __builtin_amdgcn_mfma_f32_16x16x32_bf16(a[mt], b, acc[mt][nt], 0, 0, 0);
        }
        __syncthreads();
    }

#pragma unroll
    for (int mt = 0; mt < 4; mt++)
#pragma unroll
        for (int nt = 0; nt < 4; nt++)
#pragma unroll
            for (int i = 0; i < 4; i++) {
                int row = m0 + wm * 64 + mt * 16 + quad * 4 + i;
                int col = n0 + wn * 64 + nt * 16 + m15;
                C[(size_t)row * 3072 + col] = f2bf(acc[mt][nt][i]);
            }
}

// ---------------------------------------------------------------------------
// RelPosBias body (v5, harness-verified).
// biasb stored swizzled: idx = row*2048 + (col&~63) + (col&15)*4 + ((col>>4)&3)
// Output = (mlp(rel)+b3)*log2(e) as bf16.
// ---------------------------------------------------------------------------
__device__ __forceinline__ void rpb_body(int bx,
                                         const float* __restrict__ rel,
                                         const float* __restrict__ w1,
                                         const float* __restrict__ b1,
                                         const float* __restrict__ w2,
                                         const float* __restrict__ b2,
                                         const float* __restrict__ w3,
                                         const float* __restrict__ b3,
                                         unsigned short* __restrict__ biasb) {
    const int tid = threadIdx.x;
    const int wave = tid >> 6;
    const int lane = tid & 63;
    const int m15 = lane & 15;
    const int quad = lane >> 4;

    bf16x8 af0, af1;
    {
        unsigned short t0[8], t1[8];
#pragma unroll
        for (int j = 0; j < 8; j++) {
            int k = quad * 8 + j;
            t0[j] = f2bf(w2[k * 32 + m15]);
            t1[j] = f2bf(w2[k * 32 + 16 + m15]);
        }
        af0 = *reinterpret_cast<bf16x8*>(t0);
        af1 = *reinterpret_cast<bf16x8*>(t1);
    }

    float2v w1a2[4], w1b2[4], b12[4];
#pragma unroll
    for (int p = 0; p < 4; p++) {
        int base = quad * 8 + 2 * p;
        w1a2[p] = {w1[base], w1[base + 1]};
        w1b2[p] = {w1[32 + base], w1[32 + base + 1]};
        b12[p]  = {b1[base], b1[base + 1]};
    }

    floatx4 b2r0, b2r1;
    float2v w3p00, w3p01, w3p10, w3p11;
    const float LOG2E = 1.44269504f;
    {
        float4 t0 = *reinterpret_cast<const float4*>(b2 + quad * 4);
        float4 t1 = *reinterpret_cast<const float4*>(b2 + 16 + quad * 4);
        b2r0 = {t0.x, t0.y, t0.z, t0.w};
        b2r1 = {t1.x, t1.y, t1.z, t1.w};
        float4 u0 = *reinterpret_cast<const float4*>(w3 + quad * 4);
        float4 u1 = *reinterpret_cast<const float4*>(w3 + 16 + quad * 4);
        w3p00 = {u0.x * LOG2E, u0.y * LOG2E};
        w3p01 = {u0.z * LOG2E, u0.w * LOG2E};
        w3p10 = {u1.x * LOG2E, u1.y * LOG2E};
        w3p11 = {u1.z * LOG2E, u1.w * LOG2E};
    }
    const float b3s = b3[0] * LOG2E;
    const float2v z2 = {0.f, 0.f};
    const floatx4 b3r = {b3s, b3s, b3s, b3s};

    bf16x8 sel;
    {
        unsigned short t[8];
#pragma unroll
        for (int j = 0; j < 8; j++)
            t[j] = (m15 == j) ? (unsigned short)0x3f80u : (unsigned short)0;
        sel = *reinterpret_cast<bf16x8*>(t);
    }

    const int base = bx * 1024 + wave * 64;

    float2 cur[4];
#pragma unroll
    for (int t = 0; t < 4; t++)
        cur[t] = *reinterpret_cast<const float2*>(rel + (size_t)(base + t * 16 + m15) * 2);

    for (int it = 0; it < 4; ++it) {
        const int pix0 = base + it * 256;
        float2 nxt[4];
        if (it < 3) {
#pragma unroll
            for (int t = 0; t < 4; t++)
                nxt[t] = *reinterpret_cast<const float2*>(rel + (size_t)(pix0 + 256 + t * 16 + m15) * 2);
        }

        float sreg[4];
#pragma unroll
        for (int t = 0; t < 4; t++) {
            float2v dx2 = {cur[t].x, cur[t].x}, dy2 = {cur[t].y, cur[t].y};

            unsigned int hp[4];
#pragma unroll
            for (int p = 0; p < 4; p++) {
                float2v h = __builtin_elementwise_fma(dx2, w1a2[p],
                             __builtin_elementwise_fma(dy2, w1b2[p], b12[p]));
                h = __builtin_elementwise_max(h, z2);
                hp[p] = __builtin_amdgcn_perm(__float_as_uint(h.y), __float_as_uint(h.x), 0x07060302u);
            }
            bf16x8 hb = *reinterpret_cast<bf16x8*>(hp);

            floatx4 d0 = __builtin_amdgcn_mfma_f32_16x16x32_bf16(af0, hb, b2r0, 0, 0, 0);
            floatx4 d1 = __builtin_amdgcn_mfma_f32_16x16x32_bf16(af1, hb, b2r1, 0, 0, 0);

            float2v m00 = __builtin_elementwise_max(__builtin_shufflevector(d0, d0, 0, 1), z2);
            float2v m01 = __builtin_elementwise_max(__builtin_shufflevector(d0, d0, 2, 3), z2);
            float2v m10 = __builtin_elementwise_max(__builtin_shufflevector(d1, d1, 0, 1), z2);
            float2v m11 = __builtin_elementwise_max(__builtin_shufflevector(d1, d1, 2, 3), z2);
            float2v acc2 = m00 * w3p00;
            acc2 = __builtin_elementwise_fma(m01, w3p01, acc2);
            acc2 = __builtin_elementwise_fma(m10, w3p10, acc2);
            acc2 = __builtin_elementwise_fma(m11, w3p11, acc2);
            sreg[t] = acc2.x + acc2.y;
        }

        unsigned int sb[4];
        sb[0] = (unsigned int)f2bf(sreg[0]) | ((unsigned int)f2bf(sreg[1]) << 16);
        sb[1] = (unsigned int)f2bf(sreg[2]) | ((unsigned int)f2bf(sreg[3]) << 16);
        sb[2] = 0; sb[3] = 0;
        bf16x8 sf = *reinterpret_cast<bf16x8*>(sb);
        floatx4 dsum = __builtin_amdgcn_mfma_f32_16x16x32_bf16(sel, sf, b3r, 0, 0, 0);

        if (quad == 0) {
            unsigned short o[4] = {f2bf(dsum[0]), f2bf(dsum[1]), f2bf(dsum[2]), f2bf(dsum[3])};
            *reinterpret_cast<ushort4*>(biasb + (size_t)pix0 + m15 * 4) =
                *reinterpret_cast<const ushort4*>(o);
        }

        if (it < 3) {
#pragma unroll
            for (int t = 0; t < 4; t++) cur[t] = nxt[t];
        }
    }
}

// ---------------------------------------------------------------------------
// Fused dispatch (R1-measured structure): blocks [0,384) = qkv GEMM,
// [384,4480) = rpb. Independent data; complementary pipes.
// ---------------------------------------------------------------------------
__global__ __launch_bounds__(256) void gemm_rpb(const unsigned short* __restrict__ xb,
                                                const unsigned short* __restrict__ wqT,
                                                unsigned short* __restrict__ qkv,
                                                const float* __restrict__ rel,
                                                const float* __restrict__ w1,
                                                const float* __restrict__ b1,
                                                const float* __restrict__ w2,
                                                const float* __restrict__ b2,
                                                const float* __restrict__ w3,
                                                const float* __restrict__ b3,
                                                unsigned short* __restrict__ biasb) {
    __shared__ __align__(16) unsigned short S[4 * 128 * 32];  // 32 KiB dbuf
    const int b = blockIdx.x;
    if (b < 384)
        gemm128_body(xb, wqT, qkv, b % 24, b / 24, S);
    else
        rpb_body(b - 384, rel, w1, b1, w2, b2, w3, b3, biasb);
}

// ---------------------------------------------------------------------------
// GEMM: BM=64 (used for proj), 2-phase double-buffered (R1-measured).
// ---------------------------------------------------------------------------
template<int BN, typename TC>
__global__ __launch_bounds__(256) void gemm_abt(const unsigned short* __restrict__ A,
                                                const unsigned short* __restrict__ Bt,
                                                TC* __restrict__ C,
                                                int M, int N, int K) {
    constexpr int NT = BN / 32;
    __shared__ __align__(16) unsigned short As[2][64 * 32];
    __shared__ __align__(16) unsigned short Bs[2][BN * 32];

    const int tid = threadIdx.x;
    const int wave = tid >> 6;
    const int lane = tid & 63;
    const int m15 = lane & 15;
    const int quad = lane >> 4;
    const int wm = wave >> 1;
    const int wn = wave & 1;
    const int m0 = blockIdx.y * 64;
    const int n0 = blockIdx.x * BN;

    const int srow = lane >> 2;
    const int scol = (lane & 3) * 8;

    floatx4 acc[2][NT];
#pragma unroll
    for (int mt = 0; mt < 2; mt++)
#pragma unroll
        for (int nt = 0; nt < NT; nt++) acc[mt][nt] = {0.f, 0.f, 0.f, 0.f};

    auto stage = [&](int k0, int buf) {
        gld_lds16(A + (size_t)(m0 + wave * 16 + srow) * K + k0 + scol, &As[buf][wave * 16 * 32]);
#pragma unroll
        for (int i = 0; i < BN / 64; i++) {
            int j = wave * (BN / 64) + i;
            gld_lds16(Bt + (size_t)(n0 + j * 16 + srow) * K + k0 + scol, &Bs[buf][j * 16 * 32]);
        }
    };

    const int nk = K >> 5;
    stage(0, 0);
    __syncthreads();

    for (int kk = 0; kk < nk; ++kk) {
        const int cur = kk & 1;
        if (kk + 1 < nk) stage((kk + 1) * 32, cur ^ 1);

        bf16x8 a[2];
#pragma unroll
        for (int mt = 0; mt < 2; mt++)
            a[mt] = *reinterpret_cast<bf16x8*>(&As[cur][(wm * 32 + mt * 16 + m15) * 32 + quad * 8]);
#pragma unroll
        for (int nt = 0; nt < NT; nt++) {
            bf16x8 b = *reinterpret_cast<bf16x8*>(&Bs[cur][(wn * (BN / 2) + nt * 16 + m15) * 32 + quad * 8]);
#pragma unroll
            for (int mt = 0; mt < 2; mt++)
                acc[mt][nt] = __builtin_amdgcn_mfma_f32_16x16x32_bf16(a[mt], b, acc[mt][nt], 0, 0, 0);
        }
        __syncthreads();
    }

#pragma unroll
    for (int mt = 0; mt < 2; mt++)
#pragma unroll
        for (int nt = 0; nt < NT; nt++)
#pragma unroll
            for (int i = 0; i < 4; i++) {
                int row = m0 + wm * 32 + mt * 16 + quad * 4 + i;
                int col = n0 + wn * (BN / 2) + nt * 16 + m15;
                if constexpr (std::is_same<TC, float>::value)
                    C[(size_t)row * N + col] = acc[mt][nt][i];
                else
                    C[(size_t)row * N + col] = f2bf(acc[mt][nt][i]);
            }
}

// ---------------------------------------------------------------------------
// Flash attention v4 = v3 structure (operand-swapped QK^T, register-only
// softmax/P-pack, sigma-permuted V columns, no P LDS round-trip) with the
// spill fixed: launch_bounds(512,4) (VGPR cap 128; the (512,6) bound forced
// 40 VGPR -> 290 MB/dispatch of scratch traffic, R3 post-mortem).
// ---------------------------------------------------------------------------
__global__ __launch_bounds__(512, 4) void attn_kernel(const unsigned short* __restrict__ qkv,
                                                      const unsigned short* __restrict__ biasb,
                                                      unsigned short* __restrict__ attn_out) {
    const int h = blockIdx.x;
    const int q0 = blockIdx.y * 64;
    __shared__ __align__(16) unsigned short Kst[2][64 * 72];
    __shared__ __align__(16) unsigned short Vst[2][64 * 72];  // [d][key-slot]

    const int tid = threadIdx.x;
    const int g = tid >> 8;
    const int w = (tid >> 6) & 3;
    const int lane = tid & 63;
    const int ltid = tid & 255;
    const int m15 = lane & 15;
    const int quad = lane >> 4;

    bf16x8 qf[2];
#pragma unroll
    for (int kh = 0; kh < 2; kh++)
        qf[kh] = *reinterpret_cast<const bf16x8*>(
            qkv + (size_t)(q0 + w * 16 + m15) * 3072 + h * 64 + kh * 32 + quad * 8);

    const int kr0 = ltid >> 3, kd0 = (ltid & 7) * 8;
    const int ka = (ltid & 31) * 2;
    const int vd0 = (ltid >> 5) * 8;
    // sigma(key): slot = {b5, b3, b2, b4, b1, b0}; ka even -> ska even, pair preserved
    const int ska = ((ka >> 5) & 1) * 32 + ((ka >> 2) & 3) * 8 + ((ka >> 4) & 1) * 4 + (ka & 3);

    unsigned short* Kc = Kst[g];
    unsigned short* Vc = Vst[g];
    const size_t kofs = (size_t)g * 1024;

    uint4 kreg0 = *reinterpret_cast<const uint4*>(qkv + (kofs + kr0) * 3072 + 1024 + h * 64 + kd0);
    uint4 kreg1 = *reinterpret_cast<const uint4*>(qkv + (kofs + kr0 + 32) * 3072 + 1024 + h * 64 + kd0);
    uint4 vrega = *reinterpret_cast<const uint4*>(qkv + (kofs + ka) * 3072 + 2048 + h * 64 + vd0);
    uint4 vregb = *reinterpret_cast<const uint4*>(qkv + (kofs + ka + 1) * 3072 + 2048 + h * 64 + vd0);

    // bias: 16 contiguous shorts per lane per k-tile at offset quad*16;
    // element (i*4+nt) = bias[q=m15-row][key=nt*16+quad*4+i]
    const unsigned short* bbase =
        biasb + (size_t)(q0 + w * 16 + m15) * 2048 + kofs + quad * 16;
    union BU { uint4 v[2]; unsigned short s[16]; };
    BU br, nbr;
    br.v[0] = *reinterpret_cast<const uint4*>(bbase);
    br.v[1] = *reinterpret_cast<const uint4*>(bbase + 8);

    float rs = 0.f;
    floatx4 acc[4];
#pragma unroll
    for (int i = 0; i < 4; i++) acc[i] = {0.f, 0.f, 0.f, 0.f};
    const float c1 = 0.125f * 1.44269504f;

    for (int kt = 0; kt < 16; ++kt) {
        __syncthreads();

        *reinterpret_cast<uint4*>(&Kc[kr0 * 72 + kd0]) = kreg0;
        *reinterpret_cast<uint4*>(&Kc[(kr0 + 32) * 72 + kd0]) = kreg1;
        {
            const unsigned int* aw = reinterpret_cast<const unsigned int*>(&vrega);
            const unsigned int* bw = reinterpret_cast<const unsigned int*>(&vregb);
#pragma unroll
            for (int wd = 0; wd < 4; wd++) {
                unsigned int lo = __builtin_amdgcn_perm(bw[wd], aw[wd], 0x05040100u);
                unsigned int hi = __builtin_amdgcn_perm(bw[wd], aw[wd], 0x07060302u);
                *reinterpret_cast<unsigned int*>(&Vc[(vd0 + 2 * wd) * 72 + ska]) = lo;
                *reinterpret_cast<unsigned int*>(&Vc[(vd0 + 2 * wd + 1) * 72 + ska]) = hi;
            }
        }
        __syncthreads();

        if (kt < 15) {
            const size_t kb = kofs + (size_t)(kt + 1) * 64;
            kreg0 = *reinterpret_cast<const uint4*>(qkv + (kb + kr0) * 3072 + 1024 + h * 64 + kd0);
            kreg1 = *reinterpret_cast<const uint4*>(qkv + (kb + kr0 + 32) * 3072 + 1024 + h * 64 + kd0);
            vrega = *reinterpret_cast<const uint4*>(qkv + (kb + ka) * 3072 + 2048 + h * 64 + vd0);
            vregb = *reinterpret_cast<const uint4*>(qkv + (kb + ka + 1) * 3072 + 2048 + h * 64 + vd0);
        }

        // swapped QK^T: st[nt][i] = S[key=nt*16+quad*4+i][q=m15]
        floatx4 st[4];
#pragma unroll
        for (int nt = 0; nt < 4; nt++) st[nt] = {0.f, 0.f, 0.f, 0.f};
        __builtin_amdgcn_s_setprio(1);
#pragma unroll
        for (int kh = 0; kh < 2; kh++) {
#pragma unroll
            for (int nt = 0; nt < 4; nt++) {
                bf16x8 kb = *reinterpret_cast<bf16x8*>(&Kc[(nt * 16 + m15) * 72 + kh * 32 + quad * 8]);
                st[nt] = __builtin_amdgcn_mfma_f32_16x16x32_bf16(kb, qf[kh], st[nt], 0, 0, 0);
            }
        }
        __builtin_amdgcn_s_setprio(0);

        if (kt < 15) {
            const unsigned short* nb = bbase + (size_t)(kt + 1) * 64;
            nbr.v[0] = *reinterpret_cast<const uint4*>(nb);
            nbr.v[1] = *reinterpret_cast<const uint4*>(nb + 8);
        }

        float p[4][4];
#pragma unroll
        for (int nt = 0; nt < 4; nt++)
#pragma unroll
            for (int i = 0; i < 4; i++) {
                float lg = fmaf(st[nt][i], c1, bf2f(br.s[i * 4 + nt]));
                p[nt][i] = __builtin_amdgcn_exp2f(lg);
                rs += p[nt][i];
            }

        // pack P into PV A-frags: slot j (kh,quad) -> p[2kh + (j>>2)][j&3] (local!)
        bf16x8 paf[2];
#pragma unroll
        for (int kh = 0; kh < 2; kh++) {
            unsigned int pw[4];
            pw[0] = pk2bf(p[2 * kh][0], p[2 * kh][1]);
            pw[1] = pk2bf(p[2 * kh][2], p[2 * kh][3]);
            pw[2] = pk2bf(p[2 * kh + 1][0], p[2 * kh + 1][1]);
            pw[3] = pk2bf(p[2 * kh + 1][2], p[2 * kh + 1][3]);
            paf[kh] = *reinterpret_cast<bf16x8*>(pw);
        }

        __builtin_amdgcn_s_setprio(1);
#pragma unroll
        for (int kh = 0; kh < 2; kh++) {
#pragma unroll
            for (int nt = 0; nt < 4; nt++) {
                bf16x8 vb = *reinterpret_cast<bf16x8*>(&Vc[(nt * 16 + m15) * 72 + kh * 32 + quad * 8]);
                acc[nt] = __builtin_amdgcn_mfma_f32_16x16x32_bf16(paf[kh], vb, acc[nt], 0, 0, 0);
            }
        }
        __builtin_amdgcn_s_setprio(0);

        if (kt < 15) { br.v[0] = nbr.v[0]; br.v[1] = nbr.v[1]; }
    }

    // reduce rs across quads: lane then holds full sum for q=m15 (this g)
    rs += __shfl_xor(rs, 16);
    rs += __shfl_xor(rs, 32);

    float* accbuf = reinterpret_cast<float*>(&Kst[0][0]);
    float* lbuf = accbuf + 4096;

    __syncthreads();
    if (g == 1) {
#pragma unroll
        for (int nt = 0; nt < 4; nt++)
#pragma unroll
            for (int i = 0; i < 4; i++)
                accbuf[(w * 16 + quad * 4 + i) * 64 + nt * 16 + m15] = acc[nt][i];
        if (lane < 16) lbuf[w * 16 + m15] = rs;
    }
    __syncthreads();
    if (g == 0) {
        float rq = rs + lbuf[w * 16 + m15];  // total for q=m15
        float linv[4];
#pragma unroll
        for (int i = 0; i < 4; i++)
            linv[i] = 1.f / __shfl(rq, quad * 4 + i);
#pragma unroll
        for (int nt = 0; nt < 4; nt++)
#pragma unroll
            for (int i = 0; i < 4; i++) {
                float o = (acc[nt][i] + accbuf[(w * 16 + quad * 4 + i) * 64 + nt * 16 + m15]) * linv[i];
                int row = q0 + w * 16 + quad * 4 + i;
                int col = h * 64 + nt * 16 + m15;
                attn_out[(size_t)row * 1024 + col] = f2bf(o);
            }
    }
}

extern "C" void kernel_launch(void* const* d_in, const int* in_sizes, int n_in,
                              void* d_out, int out_size, void* d_ws, size_t ws_size,
                              hipStream_t stream) {
    const float* x      = (const float*)d_in[0];
    const float* rel    = (const float*)d_in[1];
    const float* w_qkv  = (const float*)d_in[2];
    const float* w_proj = (const float*)d_in[3];
    const float* w1     = (const float*)d_in[4];
    const float* b1     = (const float*)d_in[5];
    const float* w2     = (const float*)d_in[6];
    const float* b2     = (const float*)d_in[7];
    const float* w3     = (const float*)d_in[8];
    const float* b3     = (const float*)d_in[9];

    char* ws = (char*)d_ws;
    unsigned short* qkv   = (unsigned short*)ws;                   // 12,582,912 B
    unsigned short* biasb = (unsigned short*)(ws + 12582912);      //  8,388,608 B (bf16, *log2e, swizzled)
    unsigned short* xb    = (unsigned short*)(ws + 20971520);      //  4,194,304 B (aliased with attn)
    unsigned short* attn  = xb;                                    //  xb dead after qkv GEMM
    unsigned short* wqT   = (unsigned short*)(ws + 25165824);      //  6,291,456 B
    unsigned short* wpT   = (unsigned short*)(ws + 31457280);      //  2,097,152 B  (= 32 MiB total)
    float* out = (float*)d_out;

    prep<<<5120, 256, 0, stream>>>(x, xb, w_qkv, wqT, w_proj, wpT);
    // fused: qkv GEMM (blocks 0-383) + RPB MLP (blocks 384-4479)
    gemm_rpb<<<4480, 256, 0, stream>>>(xb, wqT, qkv, rel, w1, b1, w2, b2, w3, b3, biasb);
    attn_kernel<<<dim3(16, 32), 512, 0, stream>>>(qkv, biasb, attn);
    gemm_abt<64, float><<<dim3(16, 32), 256, 0, stream>>>(attn, wpT, out, 2048, 1024, 1024);
}

// Round 5
// 198.961 us; speedup vs baseline: 1.3741x; 1.0326x over previous
//
#include <hip/hip_runtime.h>
#include <hip/hip_bf16.h>
#include <type_traits>

typedef __attribute__((ext_vector_type(8))) short bf16x8;
typedef __attribute__((ext_vector_type(4))) float floatx4;
typedef __attribute__((ext_vector_type(2))) float float2v;

__device__ __forceinline__ float bf2f(unsigned short u) {
    union { unsigned int x; float f; } v; v.x = ((unsigned int)u) << 16; return v.f;
}
__device__ __forceinline__ unsigned short f2bf(float f) {
    union { float f; unsigned int u; } v; v.f = f;
    unsigned int x = v.u;
    unsigned int r = x + 0x7fffu + ((x >> 16) & 1u);
    return (unsigned short)(r >> 16);
}
// packed f32x2 -> bf16x2 (RNE); compiler emits v_cvt_pk_bf16_f32
__device__ __forceinline__ unsigned int pk2bf(float lo, float hi) {
    float2 t; t.x = lo; t.y = hi;
    __hip_bfloat162 h = __float22bfloat162_rn(t);
    return *reinterpret_cast<unsigned int*>(&h);
}

// async global->LDS, 16B per lane; lds base must be wave-uniform (HW adds lane*16)
typedef const __attribute__((address_space(1))) unsigned int u32_g;
typedef __attribute__((address_space(3))) unsigned int u32_l;
__device__ __forceinline__ void gld_lds16(const void* g, void* l) {
    __builtin_amdgcn_global_load_lds((u32_g*)g, (u32_l*)l, 16, 0, 0);
}

// ---------------------------------------------------------------------------
// prep: fused  x->bf16 convert  +  w_qkv^T->bf16  +  w_proj^T->bf16
// ---------------------------------------------------------------------------
__device__ __forceinline__ void trans32(const float* __restrict__ in,
                                        unsigned short* __restrict__ out,
                                        int K, int N, int bx, int by,
                                        unsigned short (*T)[33]) {
    const int n0 = bx * 32, k0 = by * 32;
    const int r = threadIdx.x >> 3;
    const int c4 = (threadIdx.x & 7) * 4;
    float4 v = *reinterpret_cast<const float4*>(in + (size_t)(k0 + r) * N + n0 + c4);
    T[c4 + 0][r] = f2bf(v.x);
    T[c4 + 1][r] = f2bf(v.y);
    T[c4 + 2][r] = f2bf(v.z);
    T[c4 + 3][r] = f2bf(v.w);
    __syncthreads();
    ushort4 o = {T[r][c4], T[r][c4 + 1], T[r][c4 + 2], T[r][c4 + 3]};
    *reinterpret_cast<ushort4*>(out + (size_t)(n0 + r) * K + k0 + c4) = o;
}

__global__ __launch_bounds__(256) void prep(const float* __restrict__ x,
                                            unsigned short* __restrict__ xb,
                                            const float* __restrict__ wq,
                                            unsigned short* __restrict__ wqT,
                                            const float* __restrict__ wp,
                                            unsigned short* __restrict__ wpT) {
    __shared__ unsigned short T[32][33];
    const int b = blockIdx.x;
    if (b < 1024) {
        size_t i = ((size_t)b * 256 + threadIdx.x) * 8;
        float4 a = *reinterpret_cast<const float4*>(x + i);
        float4 c = *reinterpret_cast<const float4*>(x + i + 4);
        unsigned short t[8] = {f2bf(a.x), f2bf(a.y), f2bf(a.z), f2bf(a.w),
                               f2bf(c.x), f2bf(c.y), f2bf(c.z), f2bf(c.w)};
        *reinterpret_cast<uint4*>(xb + i) = *reinterpret_cast<const uint4*>(t);
    } else if (b < 4096) {
        int t = b - 1024;
        trans32(wq, wqT, 1024, 3072, t % 96, t / 96, T);
    } else {
        int t = b - 4096;
        trans32(wp, wpT, 1024, 1024, t % 32, t / 32, T);
    }
}

// ---------------------------------------------------------------------------
// gemm 128x64 body (BK=32, single-buffered): acc[4][2] = 32 AGPR per thread
// (was 128x128/acc[4][4]=64). The fused kernel's register allocation is
// shared by the 4096 rpb blocks; halving the accumulator lifts the whole
// kernel from 3 to 4 waves/SIMD (R4 post-mortem: occupancy 27% was the
// rpb latency-hiding cap). Extra A-panel refetches are L2-resident (A=4MB).
// Double-buffer dropped: measured neutral (R1) and it would push LDS to 48KB.
// ---------------------------------------------------------------------------
__device__ __forceinline__ void gemm12864_body(const unsigned short* __restrict__ A,
                                               const unsigned short* __restrict__ Bt,
                                               unsigned short* __restrict__ C,
                                               int bx, int by,
                                               unsigned short* __restrict__ S) {
    const int tid = threadIdx.x;
    const int wave = tid >> 6;
    const int lane = tid & 63;
    const int m15 = lane & 15;
    const int quad = lane >> 4;
    const int wm = wave >> 1;
    const int wn = wave & 1;
    const int m0 = by * 128;
    const int n0 = bx * 64;
    const int srow = lane >> 2;
    const int scol = (lane & 3) * 8;

    unsigned short* As = S;             // 128 x 32
    unsigned short* Bs = S + 128 * 32;  //  64 x 32

    floatx4 acc[4][2];
#pragma unroll
    for (int mt = 0; mt < 4; mt++)
#pragma unroll
        for (int nt = 0; nt < 2; nt++) acc[mt][nt] = {0.f, 0.f, 0.f, 0.f};

    for (int k0 = 0; k0 < 1024; k0 += 32) {
#pragma unroll
        for (int i = 0; i < 2; i++) {
            int j = wave * 2 + i;
            gld_lds16(A + (size_t)(m0 + j * 16 + srow) * 1024 + k0 + scol, &As[j * 16 * 32]);
        }
        gld_lds16(Bt + (size_t)(n0 + wave * 16 + srow) * 1024 + k0 + scol, &Bs[wave * 16 * 32]);
        __syncthreads();

        bf16x8 a[4];
#pragma unroll
        for (int mt = 0; mt < 4; mt++)
            a[mt] = *reinterpret_cast<bf16x8*>(&As[(wm * 64 + mt * 16 + m15) * 32 + quad * 8]);
#pragma unroll
        for (int nt = 0; nt < 2; nt++) {
            bf16x8 b = *reinterpret_cast<bf16x8*>(&Bs[(wn * 32 + nt * 16 + m15) * 32 + quad * 8]);
#pragma unroll
            for (int mt = 0; mt < 4; mt++)
                acc[mt][nt] = __builtin_amdgcn_mfma_f32_16x16x32_bf16(a[mt], b, acc[mt][nt], 0, 0, 0);
        }
        __syncthreads();
    }

#pragma unroll
    for (int mt = 0; mt < 4; mt++)
#pragma unroll
        for (int nt = 0; nt < 2; nt++)
#pragma unroll
            for (int i = 0; i < 4; i++) {
                int row = m0 + wm * 64 + mt * 16 + quad * 4 + i;
                int col = n0 + wn * 32 + nt * 16 + m15;
                C[(size_t)row * 3072 + col] = f2bf(acc[mt][nt][i]);
            }
}

// ---------------------------------------------------------------------------
// RelPosBias body (v5 logic, harness-verified).
// biasb stored swizzled: idx = row*2048 + (col&~63) + (col&15)*4 + ((col>>4)&3)
// Output = (mlp(rel)+b3)*log2(e) as bf16.
// ---------------------------------------------------------------------------
__device__ __forceinline__ void rpb_body(int bx,
                                         const float* __restrict__ rel,
                                         const float* __restrict__ w1,
                                         const float* __restrict__ b1,
                                         const float* __restrict__ w2,
                                         const float* __restrict__ b2,
                                         const float* __restrict__ w3,
                                         const float* __restrict__ b3,
                                         unsigned short* __restrict__ biasb) {
    const int tid = threadIdx.x;
    const int wave = tid >> 6;
    const int lane = tid & 63;
    const int m15 = lane & 15;
    const int quad = lane >> 4;

    bf16x8 af0, af1;
    {
        unsigned short t0[8], t1[8];
#pragma unroll
        for (int j = 0; j < 8; j++) {
            int k = quad * 8 + j;
            t0[j] = f2bf(w2[k * 32 + m15]);
            t1[j] = f2bf(w2[k * 32 + 16 + m15]);
        }
        af0 = *reinterpret_cast<bf16x8*>(t0);
        af1 = *reinterpret_cast<bf16x8*>(t1);
    }

    float2v w1a2[4], w1b2[4], b12[4];
#pragma unroll
    for (int p = 0; p < 4; p++) {
        int base = quad * 8 + 2 * p;
        w1a2[p] = {w1[base], w1[base + 1]};
        w1b2[p] = {w1[32 + base], w1[32 + base + 1]};
        b12[p]  = {b1[base], b1[base + 1]};
    }

    floatx4 b2r0, b2r1;
    float2v w3p00, w3p01, w3p10, w3p11;
    const float LOG2E = 1.44269504f;
    {
        float4 t0 = *reinterpret_cast<const float4*>(b2 + quad * 4);
        float4 t1 = *reinterpret_cast<const float4*>(b2 + 16 + quad * 4);
        b2r0 = {t0.x, t0.y, t0.z, t0.w};
        b2r1 = {t1.x, t1.y, t1.z, t1.w};
        float4 u0 = *reinterpret_cast<const float4*>(w3 + quad * 4);
        float4 u1 = *reinterpret_cast<const float4*>(w3 + 16 + quad * 4);
        w3p00 = {u0.x * LOG2E, u0.y * LOG2E};
        w3p01 = {u0.z * LOG2E, u0.w * LOG2E};
        w3p10 = {u1.x * LOG2E, u1.y * LOG2E};
        w3p11 = {u1.z * LOG2E, u1.w * LOG2E};
    }
    const float b3s = b3[0] * LOG2E;
    const float2v z2 = {0.f, 0.f};
    const floatx4 b3r = {b3s, b3s, b3s, b3s};

    bf16x8 sel;
    {
        unsigned short t[8];
#pragma unroll
        for (int j = 0; j < 8; j++)
            t[j] = (m15 == j) ? (unsigned short)0x3f80u : (unsigned short)0;
        sel = *reinterpret_cast<bf16x8*>(t);
    }

    const int base = bx * 1024 + wave * 64;

    float2 cur[4];
#pragma unroll
    for (int t = 0; t < 4; t++)
        cur[t] = *reinterpret_cast<const float2*>(rel + (size_t)(base + t * 16 + m15) * 2);

    for (int it = 0; it < 4; ++it) {
        const int pix0 = base + it * 256;
        float2 nxt[4];
        if (it < 3) {
#pragma unroll
            for (int t = 0; t < 4; t++)
                nxt[t] = *reinterpret_cast<const float2*>(rel + (size_t)(pix0 + 256 + t * 16 + m15) * 2);
        }

        float sreg[4];
#pragma unroll
        for (int t = 0; t < 4; t++) {
            float2v dx2 = {cur[t].x, cur[t].x}, dy2 = {cur[t].y, cur[t].y};

            unsigned int hp[4];
#pragma unroll
            for (int p = 0; p < 4; p++) {
                float2v h = __builtin_elementwise_fma(dx2, w1a2[p],
                             __builtin_elementwise_fma(dy2, w1b2[p], b12[p]));
                h = __builtin_elementwise_max(h, z2);
                hp[p] = __builtin_amdgcn_perm(__float_as_uint(h.y), __float_as_uint(h.x), 0x07060302u);
            }
            bf16x8 hb = *reinterpret_cast<bf16x8*>(hp);

            floatx4 d0 = __builtin_amdgcn_mfma_f32_16x16x32_bf16(af0, hb, b2r0, 0, 0, 0);
            floatx4 d1 = __builtin_amdgcn_mfma_f32_16x16x32_bf16(af1, hb, b2r1, 0, 0, 0);

            float2v m00 = __builtin_elementwise_max(__builtin_shufflevector(d0, d0, 0, 1), z2);
            float2v m01 = __builtin_elementwise_max(__builtin_shufflevector(d0, d0, 2, 3), z2);
            float2v m10 = __builtin_elementwise_max(__builtin_shufflevector(d1, d1, 0, 1), z2);
            float2v m11 = __builtin_elementwise_max(__builtin_shufflevector(d1, d1, 2, 3), z2);
            float2v acc2 = m00 * w3p00;
            acc2 = __builtin_elementwise_fma(m01, w3p01, acc2);
            acc2 = __builtin_elementwise_fma(m10, w3p10, acc2);
            acc2 = __builtin_elementwise_fma(m11, w3p11, acc2);
            sreg[t] = acc2.x + acc2.y;
        }

        unsigned int sb[4];
        sb[0] = pk2bf(sreg[0], sreg[1]);
        sb[1] = pk2bf(sreg[2], sreg[3]);
        sb[2] = 0; sb[3] = 0;
        bf16x8 sf = *reinterpret_cast<bf16x8*>(sb);
        floatx4 dsum = __builtin_amdgcn_mfma_f32_16x16x32_bf16(sel, sf, b3r, 0, 0, 0);

        if (quad == 0) {
            unsigned short o[4] = {f2bf(dsum[0]), f2bf(dsum[1]), f2bf(dsum[2]), f2bf(dsum[3])};
            *reinterpret_cast<ushort4*>(biasb + (size_t)pix0 + m15 * 4) =
                *reinterpret_cast<const ushort4*>(o);
        }

        if (it < 3) {
#pragma unroll
            for (int t = 0; t < 4; t++) cur[t] = nxt[t];
        }
    }
}

// ---------------------------------------------------------------------------
// Fused dispatch: blocks [0,768) = qkv GEMM (128x64 tiles), [768,4864) = rpb.
// launch_bounds(256,4): 4 waves/SIMD (VGPR cap 128; gemm ~108, rpb ~76).
// ---------------------------------------------------------------------------
__global__ __launch_bounds__(256, 4) void gemm_rpb(const unsigned short* __restrict__ xb,
                                                   const unsigned short* __restrict__ wqT,
                                                   unsigned short* __restrict__ qkv,
                                                   const float* __restrict__ rel,
                                                   const float* __restrict__ w1,
                                                   const float* __restrict__ b1,
                                                   const float* __restrict__ w2,
                                                   const float* __restrict__ b2,
                                                   const float* __restrict__ w3,
                                                   const float* __restrict__ b3,
                                                   unsigned short* __restrict__ biasb) {
    __shared__ __align__(16) unsigned short S[(128 + 64) * 32];  // 12 KiB
    const int b = blockIdx.x;
    if (b < 768)
        gemm12864_body(xb, wqT, qkv, b % 48, b / 48, S);
    else
        rpb_body(b - 768, rel, w1, b1, w2, b2, w3, b3, biasb);
}

// ---------------------------------------------------------------------------
// GEMM: BM=64 (used for proj), 2-phase double-buffered (R1-measured).
// ---------------------------------------------------------------------------
template<int BN, typename TC>
__global__ __launch_bounds__(256) void gemm_abt(const unsigned short* __restrict__ A,
                                                const unsigned short* __restrict__ Bt,
                                                TC* __restrict__ C,
                                                int M, int N, int K) {
    constexpr int NT = BN / 32;
    __shared__ __align__(16) unsigned short As[2][64 * 32];
    __shared__ __align__(16) unsigned short Bs[2][BN * 32];

    const int tid = threadIdx.x;
    const int wave = tid >> 6;
    const int lane = tid & 63;
    const int m15 = lane & 15;
    const int quad = lane >> 4;
    const int wm = wave >> 1;
    const int wn = wave & 1;
    const int m0 = blockIdx.y * 64;
    const int n0 = blockIdx.x * BN;

    const int srow = lane >> 2;
    const int scol = (lane & 3) * 8;

    floatx4 acc[2][NT];
#pragma unroll
    for (int mt = 0; mt < 2; mt++)
#pragma unroll
        for (int nt = 0; nt < NT; nt++) acc[mt][nt] = {0.f, 0.f, 0.f, 0.f};

    auto stage = [&](int k0, int buf) {
        gld_lds16(A + (size_t)(m0 + wave * 16 + srow) * K + k0 + scol, &As[buf][wave * 16 * 32]);
#pragma unroll
        for (int i = 0; i < BN / 64; i++) {
            int j = wave * (BN / 64) + i;
            gld_lds16(Bt + (size_t)(n0 + j * 16 + srow) * K + k0 + scol, &Bs[buf][j * 16 * 32]);
        }
    };

    const int nk = K >> 5;
    stage(0, 0);
    __syncthreads();

    for (int kk = 0; kk < nk; ++kk) {
        const int cur = kk & 1;
        if (kk + 1 < nk) stage((kk + 1) * 32, cur ^ 1);

        bf16x8 a[2];
#pragma unroll
        for (int mt = 0; mt < 2; mt++)
            a[mt] = *reinterpret_cast<bf16x8*>(&As[cur][(wm * 32 + mt * 16 + m15) * 32 + quad * 8]);
#pragma unroll
        for (int nt = 0; nt < NT; nt++) {
            bf16x8 b = *reinterpret_cast<bf16x8*>(&Bs[cur][(wn * (BN / 2) + nt * 16 + m15) * 32 + quad * 8]);
#pragma unroll
            for (int mt = 0; mt < 2; mt++)
                acc[mt][nt] = __builtin_amdgcn_mfma_f32_16x16x32_bf16(a[mt], b, acc[mt][nt], 0, 0, 0);
        }
        __syncthreads();
    }

#pragma unroll
    for (int mt = 0; mt < 2; mt++)
#pragma unroll
        for (int nt = 0; nt < NT; nt++)
#pragma unroll
            for (int i = 0; i < 4; i++) {
                int row = m0 + wm * 32 + mt * 16 + quad * 4 + i;
                int col = n0 + wn * (BN / 2) + nt * 16 + m15;
                if constexpr (std::is_same<TC, float>::value)
                    C[(size_t)row * N + col] = acc[mt][nt][i];
                else
                    C[(size_t)row * N + col] = f2bf(acc[mt][nt][i]);
            }
}

// ---------------------------------------------------------------------------
// Flash attention v4 (R4-verified): operand-swapped QK^T, register-only
// softmax/P-pack, sigma-permuted V columns, no P LDS round-trip.
// launch_bounds(512,4) — do NOT raise (R3: (512,6) caused 290MB spills).
// ---------------------------------------------------------------------------
__global__ __launch_bounds__(512, 4) void attn_kernel(const unsigned short* __restrict__ qkv,
                                                      const unsigned short* __restrict__ biasb,
                                                      unsigned short* __restrict__ attn_out) {
    const int h = blockIdx.x;
    const int q0 = blockIdx.y * 64;
    __shared__ __align__(16) unsigned short Kst[2][64 * 72];
    __shared__ __align__(16) unsigned short Vst[2][64 * 72];  // [d][key-slot]

    const int tid = threadIdx.x;
    const int g = tid >> 8;
    const int w = (tid >> 6) & 3;
    const int lane = tid & 63;
    const int ltid = tid & 255;
    const int m15 = lane & 15;
    const int quad = lane >> 4;

    bf16x8 qf[2];
#pragma unroll
    for (int kh = 0; kh < 2; kh++)
        qf[kh] = *reinterpret_cast<const bf16x8*>(
            qkv + (size_t)(q0 + w * 16 + m15) * 3072 + h * 64 + kh * 32 + quad * 8);

    const int kr0 = ltid >> 3, kd0 = (ltid & 7) * 8;
    const int ka = (ltid & 31) * 2;
    const int vd0 = (ltid >> 5) * 8;
    // sigma(key): slot = {b5, b3, b2, b4, b1, b0}; ka even -> ska even, pair preserved
    const int ska = ((ka >> 5) & 1) * 32 + ((ka >> 2) & 3) * 8 + ((ka >> 4) & 1) * 4 + (ka & 3);

    unsigned short* Kc = Kst[g];
    unsigned short* Vc = Vst[g];
    const size_t kofs = (size_t)g * 1024;

    uint4 kreg0 = *reinterpret_cast<const uint4*>(qkv + (kofs + kr0) * 3072 + 1024 + h * 64 + kd0);
    uint4 kreg1 = *reinterpret_cast<const uint4*>(qkv + (kofs + kr0 + 32) * 3072 + 1024 + h * 64 + kd0);
    uint4 vrega = *reinterpret_cast<const uint4*>(qkv + (kofs + ka) * 3072 + 2048 + h * 64 + vd0);
    uint4 vregb = *reinterpret_cast<const uint4*>(qkv + (kofs + ka + 1) * 3072 + 2048 + h * 64 + vd0);

    // bias: 16 contiguous shorts per lane per k-tile at offset quad*16;
    // element (i*4+nt) = bias[q=m15-row][key=nt*16+quad*4+i]
    const unsigned short* bbase =
        biasb + (size_t)(q0 + w * 16 + m15) * 2048 + kofs + quad * 16;
    union BU { uint4 v[2]; unsigned short s[16]; };
    BU br, nbr;
    br.v[0] = *reinterpret_cast<const uint4*>(bbase);
    br.v[1] = *reinterpret_cast<const uint4*>(bbase + 8);

    float rs = 0.f;
    floatx4 acc[4];
#pragma unroll
    for (int i = 0; i < 4; i++) acc[i] = {0.f, 0.f, 0.f, 0.f};
    const float c1 = 0.125f * 1.44269504f;

    for (int kt = 0; kt < 16; ++kt) {
        __syncthreads();

        *reinterpret_cast<uint4*>(&Kc[kr0 * 72 + kd0]) = kreg0;
        *reinterpret_cast<uint4*>(&Kc[(kr0 + 32) * 72 + kd0]) = kreg1;
        {
            const unsigned int* aw = reinterpret_cast<const unsigned int*>(&vrega);
            const unsigned int* bw = reinterpret_cast<const unsigned int*>(&vregb);
#pragma unroll
            for (int wd = 0; wd < 4; wd++) {
                unsigned int lo = __builtin_amdgcn_perm(bw[wd], aw[wd], 0x05040100u);
                unsigned int hi = __builtin_amdgcn_perm(bw[wd], aw[wd], 0x07060302u);
                *reinterpret_cast<unsigned int*>(&Vc[(vd0 + 2 * wd) * 72 + ska]) = lo;
                *reinterpret_cast<unsigned int*>(&Vc[(vd0 + 2 * wd + 1) * 72 + ska]) = hi;
            }
        }
        __syncthreads();

        if (kt < 15) {
            const size_t kb = kofs + (size_t)(kt + 1) * 64;
            kreg0 = *reinterpret_cast<const uint4*>(qkv + (kb + kr0) * 3072 + 1024 + h * 64 + kd0);
            kreg1 = *reinterpret_cast<const uint4*>(qkv + (kb + kr0 + 32) * 3072 + 1024 + h * 64 + kd0);
            vrega = *reinterpret_cast<const uint4*>(qkv + (kb + ka) * 3072 + 2048 + h * 64 + vd0);
            vregb = *reinterpret_cast<const uint4*>(qkv + (kb + ka + 1) * 3072 + 2048 + h * 64 + vd0);
        }

        // swapped QK^T: st[nt][i] = S[key=nt*16+quad*4+i][q=m15]
        floatx4 st[4];
#pragma unroll
        for (int nt = 0; nt < 4; nt++) st[nt] = {0.f, 0.f, 0.f, 0.f};
        __builtin_amdgcn_s_setprio(1);
#pragma unroll
        for (int kh = 0; kh < 2; kh++) {
#pragma unroll
            for (int nt = 0; nt < 4; nt++) {
                bf16x8 kb = *reinterpret_cast<bf16x8*>(&Kc[(nt * 16 + m15) * 72 + kh * 32 + quad * 8]);
                st[nt] = __builtin_amdgcn_mfma_f32_16x16x32_bf16(kb, qf[kh], st[nt], 0, 0, 0);
            }
        }
        __builtin_amdgcn_s_setprio(0);

        if (kt < 15) {
            const unsigned short* nb = bbase + (size_t)(kt + 1) * 64;
            nbr.v[0] = *reinterpret_cast<const uint4*>(nb);
            nbr.v[1] = *reinterpret_cast<const uint4*>(nb + 8);
        }

        float p[4][4];
#pragma unroll
        for (int nt = 0; nt < 4; nt++)
#pragma unroll
            for (int i = 0; i < 4; i++) {
                float lg = fmaf(st[nt][i], c1, bf2f(br.s[i * 4 + nt]));
                p[nt][i] = __builtin_amdgcn_exp2f(lg);
                rs += p[nt][i];
            }

        // pack P into PV A-frags: slot j (kh,quad) -> p[2kh + (j>>2)][j&3] (local!)
        bf16x8 paf[2];
#pragma unroll
        for (int kh = 0; kh < 2; kh++) {
            unsigned int pw[4];
            pw[0] = pk2bf(p[2 * kh][0], p[2 * kh][1]);
            pw[1] = pk2bf(p[2 * kh][2], p[2 * kh][3]);
            pw[2] = pk2bf(p[2 * kh + 1][0], p[2 * kh + 1][1]);
            pw[3] = pk2bf(p[2 * kh + 1][2], p[2 * kh + 1][3]);
            paf[kh] = *reinterpret_cast<bf16x8*>(pw);
        }

        __builtin_amdgcn_s_setprio(1);
#pragma unroll
        for (int kh = 0; kh < 2; kh++) {
#pragma unroll
            for (int nt = 0; nt < 4; nt++) {
                bf16x8 vb = *reinterpret_cast<bf16x8*>(&Vc[(nt * 16 + m15) * 72 + kh * 32 + quad * 8]);
                acc[nt] = __builtin_amdgcn_mfma_f32_16x16x32_bf16(paf[kh], vb, acc[nt], 0, 0, 0);
            }
        }
        __builtin_amdgcn_s_setprio(0);

        if (kt < 15) { br.v[0] = nbr.v[0]; br.v[1] = nbr.v[1]; }
    }

    // reduce rs across quads: lane then holds full sum for q=m15 (this g)
    rs += __shfl_xor(rs, 16);
    rs += __shfl_xor(rs, 32);

    float* accbuf = reinterpret_cast<float*>(&Kst[0][0]);
    float* lbuf = accbuf + 4096;

    __syncthreads();
    if (g == 1) {
#pragma unroll
        for (int nt = 0; nt < 4; nt++)
#pragma unroll
            for (int i = 0; i < 4; i++)
                accbuf[(w * 16 + quad * 4 + i) * 64 + nt * 16 + m15] = acc[nt][i];
        if (lane < 16) lbuf[w * 16 + m15] = rs;
    }
    __syncthreads();
    if (g == 0) {
        float rq = rs + lbuf[w * 16 + m15];  // total for q=m15
        float linv[4];
#pragma unroll
        for (int i = 0; i < 4; i++)
            linv[i] = 1.f / __shfl(rq, quad * 4 + i);
#pragma unroll
        for (int nt = 0; nt < 4; nt++)
#pragma unroll
            for (int i = 0; i < 4; i++) {
                float o = (acc[nt][i] + accbuf[(w * 16 + quad * 4 + i) * 64 + nt * 16 + m15]) * linv[i];
                int row = q0 + w * 16 + quad * 4 + i;
                int col = h * 64 + nt * 16 + m15;
                attn_out[(size_t)row * 1024 + col] = f2bf(o);
            }
    }
}

extern "C" void kernel_launch(void* const* d_in, const int* in_sizes, int n_in,
                              void* d_out, int out_size, void* d_ws, size_t ws_size,
                              hipStream_t stream) {
    const float* x      = (const float*)d_in[0];
    const float* rel    = (const float*)d_in[1];
    const float* w_qkv  = (const float*)d_in[2];
    const float* w_proj = (const float*)d_in[3];
    const float* w1     = (const float*)d_in[4];
    const float* b1     = (const float*)d_in[5];
    const float* w2     = (const float*)d_in[6];
    const float* b2     = (const float*)d_in[7];
    const float* w3     = (const float*)d_in[8];
    const float* b3     = (const float*)d_in[9];

    char* ws = (char*)d_ws;
    unsigned short* qkv   = (unsigned short*)ws;                   // 12,582,912 B
    unsigned short* biasb = (unsigned short*)(ws + 12582912);      //  8,388,608 B (bf16, *log2e, swizzled)
    unsigned short* xb    = (unsigned short*)(ws + 20971520);      //  4,194,304 B (aliased with attn)
    unsigned short* attn  = xb;                                    //  xb dead after qkv GEMM
    unsigned short* wqT   = (unsigned short*)(ws + 25165824);      //  6,291,456 B
    unsigned short* wpT   = (unsigned short*)(ws + 31457280);      //  2,097,152 B  (= 32 MiB total)
    float* out = (float*)d_out;

    prep<<<5120, 256, 0, stream>>>(x, xb, w_qkv, wqT, w_proj, wpT);
    // fused: qkv GEMM 128x64 tiles (blocks 0-767) + RPB MLP (blocks 768-4863)
    gemm_rpb<<<4864, 256, 0, stream>>>(xb, wqT, qkv, rel, w1, b1, w2, b2, w3, b3, biasb);
    attn_kernel<<<dim3(16, 32), 512, 0, stream>>>(qkv, biasb, attn);
    gemm_abt<64, float><<<dim3(16, 32), 256, 0, stream>>>(attn, wpT, out, 2048, 1024, 1024);
}